// Round 1
// baseline (158.193 us; speedup 1.0000x reference)
//
#include <hip/hip_runtime.h>
#include <stdint.h>

#define LOG2E 1.4426950408889634f

typedef __bf16 v8bf __attribute__((ext_vector_type(8)));
typedef float v16f __attribute__((ext_vector_type(16)));

static constexpr int B = 4, N = 2048, FIN = 128, H = 4, DK = 32;
static constexpr int IT = N / 32;   // 64 i-tiles

__device__ __forceinline__ float exp2_fast(float x) {
#if __has_builtin(__builtin_amdgcn_exp2f)
  return __builtin_amdgcn_exp2f(x);
#else
  float r;
  asm("v_exp_f32 %0, %1" : "=v"(r) : "v"(x));
  return r;
#endif
}

__device__ __forceinline__ unsigned int bf16_rne(float f) {
  unsigned int u = __builtin_bit_cast(unsigned int, f);
  u += 0x7FFFu + ((u >> 16) & 1u);
  return u >> 16;
}

// ---------------- kernel 0: cast x->bf16 + wtb[h][d][f] bf16 ----------------
__global__ __launch_bounds__(256) void k_prep(const float* __restrict__ x,
                                              const float* __restrict__ W,
                                              unsigned short* __restrict__ xb,
                                              unsigned short* __restrict__ wtb) {
  int idx = blockIdx.x * 256 + threadIdx.x;
  constexpr int TX = B * N * FIN;          // 1048576
  if (idx < TX) {
    xb[idx] = (unsigned short)bf16_rne(x[idx]);
  } else {
    int j = idx - TX;                      // < H*DK*FIN = 16384
    int h = j >> 12, r = j & 4095, d = r >> 7, f = r & 127;
    wtb[j] = (unsigned short)bf16_rne(W[(h * FIN + f) * DK + d]);
  }
}

// ---------------- kernel 1: h projection via MFMA; h_t[bh][d][n] + el/er ----------------
__global__ __launch_bounds__(256) void k_hproj(const unsigned short* __restrict__ xb,
                                               const unsigned short* __restrict__ wtb,
                                               const float* __restrict__ a,
                                               unsigned short* __restrict__ h_t,
                                               float* __restrict__ el,
                                               float* __restrict__ er) {
  int blk = blockIdx.x;
  int b = blk >> 6, it = blk & 63;
  int tid = threadIdx.x;
  int head = tid >> 6, lane = tid & 63;
  int lrow = lane & 31, kh = lane >> 5;
  int bh = b * H + head;
  int n = it * 32 + lrow;
  const unsigned short* xp = xb + (b * N + n) * FIN + kh * 8;
  const unsigned short* wp = wtb + (head * DK + lrow) * FIN + kh * 8;
  v16f acc = {};
#pragma unroll
  for (int s = 0; s < FIN / 16; ++s) {
    v8bf av = __builtin_bit_cast(v8bf, *(const int4*)(wp + s * 16));
    v8bf bv = __builtin_bit_cast(v8bf, *(const int4*)(xp + s * 16));
    acc = __builtin_amdgcn_mfma_f32_32x32x16_bf16(av, bv, acc, 0, 0, 0);
  }
  float pel = 0.f, per = 0.f;
#pragma unroll
  for (int r = 0; r < 16; ++r) {
    int d = (r & 3) + 8 * (r >> 2) + 4 * kh;   // C/D row mapping (32x32 bf16)
    float hv = acc[r];
    h_t[(bh * DK + d) * N + n] = (unsigned short)bf16_rne(hv);
    pel = fmaf(hv, a[head * 2 * DK + d], pel);
    per = fmaf(hv, a[head * 2 * DK + DK + d], per);
  }
  pel += __shfl_xor(pel, 32);
  per += __shfl_xor(per, 32);
  if (kh == 0) {
    el[bh * N + n] = pel * LOG2E;
    er[bh * N + n] = per * LOG2E;
  }
}

// ---------------- kernel 2: fused attention over a j-half, partials to ws ----------------
// grid = B*IT*2; block = 1024 threads = 16 waves = (jq 0..3) x (head 0..3)
// each wave covers 256 j of this block's 1024-j half; raw int32 adj read inline.
// 2 blocks/CU (32 waves/CU) enforced via __launch_bounds__(1024, 8) -> VGPR <= 64.
__global__ __launch_bounds__(1024, 8) void k_attn(const int* __restrict__ adj,
                                                  const unsigned short* __restrict__ h_t,
                                                  const float* __restrict__ el,
                                                  const float* __restrict__ er,
                                                  float* __restrict__ pnum,
                                                  float* __restrict__ pden) {
  __shared__ float part4[4][H][1024];   // [jq][head][i*32+d] private slices, no atomics
  __shared__ float lsh4[4][H][32];      // [jq][head][i]
  int blk = blockIdx.x;                 // 0..511
  int bit = blk >> 1, jh = blk & 1;
  int b = bit >> 6, it = bit & 63;
  int tid = threadIdx.x;
  int wave = tid >> 6;
  int head = wave & 3, jq = wave >> 2;
  int lane = tid & 63, lrow = lane & 31, kh = lane >> 5;
  int ig = it * 32 + lrow, bh = b * H + head;

  float eli = el[bh * N + ig];
  int j0 = jh * 1024 + jq * 256 + kh * 8;
  const float* erp = er + bh * N + j0;
  const unsigned short* hp = h_t + (size_t)(bh * DK + lrow) * N + j0;
  const int* ap = adj + ((size_t)(b * N + ig)) * N + j0;

  v16f acc = {};
  float lsum = 0.f;
  // adj streams from HBM (read-once, ~900cy) -> 1-deep explicit prefetch.
  // er/h_t are L2/L3-resident (128KB/2MB), hidden by 8-wave/SIMD TLP.
  int4 A0 = *(const int4*)ap;
  int4 A1 = *(const int4*)(ap + 4);
#pragma unroll
  for (int s = 0; s < 16; ++s) {
    int o = s * 16;
    int4 a0 = A0, a1 = A1;
    if (s + 1 < 16) {
      A0 = *(const int4*)(ap + o + 16);
      A1 = *(const int4*)(ap + o + 20);
    }
    float4 ea = *(const float4*)(erp + o);
    float4 eb = *(const float4*)(erp + o + 4);
    int4 hb = *(const int4*)(hp + o);
    float ev[8] = {ea.x, ea.y, ea.z, ea.w, eb.x, eb.y, eb.z, eb.w};
    int aw[8] = {a0.x, a0.y, a0.z, a0.w, a1.x, a1.y, a1.z, a1.w};
    unsigned ub[8];
#pragma unroll
    for (int k = 0; k < 8; ++k) {
      float tt = eli + ev[k];
      tt = fmaxf(tt, 0.2f * tt);            // leaky relu (log2e pre-folded)
      float pv = exp2_fast(tt);
      unsigned u = __builtin_bit_cast(unsigned, pv) & 0xFFFF0000u;
      u = aw[k] ? u : 0u;                   // adjacency mask from raw int
      ub[k] = u;
      lsum += __builtin_bit_cast(float, u); // truncated value: num/den consistent
    }
    unsigned u0 = __builtin_amdgcn_perm(ub[1], ub[0], 0x07060302u);
    unsigned u1 = __builtin_amdgcn_perm(ub[3], ub[2], 0x07060302u);
    unsigned u2 = __builtin_amdgcn_perm(ub[5], ub[4], 0x07060302u);
    unsigned u3 = __builtin_amdgcn_perm(ub[7], ub[6], 0x07060302u);
    uint4 au = {u0, u1, u2, u3};
    v8bf av = __builtin_bit_cast(v8bf, au);
    v8bf hv = __builtin_bit_cast(v8bf, hb);
    acc = __builtin_amdgcn_mfma_f32_32x32x16_bf16(av, hv, acc, 0, 0, 0);
  }

  lsum += __shfl_xor(lsum, 32);
  if (lane < 32) lsh4[jq][head][lane] = lsum;
#pragma unroll
  for (int r = 0; r < 16; ++r) {
    int rowl = (r & 3) + 8 * (r >> 2) + 4 * kh;   // i-row within tile
    part4[jq][head][rowl * 32 + lrow] = acc[r];   // private slice: plain store
  }
  __syncthreads();

  // combine 4 jq slices; 4096 partial outputs / 1024 threads = one float4 each
  int e = tid * 4;
  int rh = e >> 10, rr = e & 1023;
  float4 q0 = *(const float4*)&part4[0][rh][rr];
  float4 q1 = *(const float4*)&part4[1][rh][rr];
  float4 q2 = *(const float4*)&part4[2][rh][rr];
  float4 q3 = *(const float4*)&part4[3][rh][rr];
  float4 s4;
  s4.x = (q0.x + q1.x) + (q2.x + q3.x);
  s4.y = (q0.y + q1.y) + (q2.y + q3.y);
  s4.z = (q0.z + q1.z) + (q2.z + q3.z);
  s4.w = (q0.w + q1.w) + (q2.w + q3.w);
  *(float4*)&pnum[(size_t)blk * 4096 + e] = s4;
  if (tid < 128) {
    float d = (lsh4[0][tid >> 5][tid & 31] + lsh4[1][tid >> 5][tid & 31]) +
              (lsh4[2][tid >> 5][tid & 31] + lsh4[3][tid >> 5][tid & 31]);
    pden[blk * 128 + tid] = d;
  }
}

// ---------------- kernel 3: combine j-halves + normalize ----------------
__global__ __launch_bounds__(1024) void k_final(const float* __restrict__ pnum,
                                                const float* __restrict__ pden,
                                                float* __restrict__ out) {
  int bit = blockIdx.x;            // 0..255 = (b, it)
  int b = bit >> 6, it = bit & 63;
  int tid = threadIdx.x;
  int e = tid * 4;
  int rh = e >> 10, ri = (e >> 5) & 31, rd = e & 31;
  size_t p0 = (size_t)(bit * 2) * 4096 + e;
  float4 n0 = *(const float4*)&pnum[p0];
  float4 n1 = *(const float4*)&pnum[p0 + 4096];
  float d = pden[bit * 2 * 128 + rh * 32 + ri] + pden[(bit * 2 + 1) * 128 + rh * 32 + ri];
  float inv = 1.0f / d;
  float4 o;
  o.x = (n0.x + n1.x) * inv;
  o.y = (n0.y + n1.y) * inv;
  o.z = (n0.z + n1.z) * inv;
  o.w = (n0.w + n1.w) * inv;
  *(float4*)&out[(size_t)((b * H + rh) * N + it * 32 + ri) * DK + rd] = o;
}

extern "C" void kernel_launch(void* const* d_in, const int* in_sizes, int n_in,
                              void* d_out, int out_size, void* d_ws, size_t ws_size,
                              hipStream_t stream) {
  const float* x = (const float*)d_in[0];
  const int* adj = (const int*)d_in[1];
  const float* W = (const float*)d_in[2];
  const float* a = (const float*)d_in[3];
  float* out = (float*)d_out;
  char* ws = (char*)d_ws;

  unsigned short* h_t = (unsigned short*)(ws);             // 2 MB   [B][H][DK][N]
  float* el = (float*)(ws + 0x200000);                     // 128 KB
  float* er = (float*)(ws + 0x220000);                     // 128 KB
  unsigned short* wtb = (unsigned short*)(ws + 0x240000);  // 32 KB
  unsigned short* xb = (unsigned short*)(ws + 0x250000);   // 2 MB
  float* pnum = (float*)(ws + 0x450000);                   // 8 MB   [512][H][32][32]
  float* pden = (float*)(ws + 0xC50000);                   // 256 KB [512][H][32]
  // total ~12.8 MB

  hipLaunchKernelGGL(k_prep, dim3((B * N * FIN + H * DK * FIN) / 256), dim3(256), 0, stream,
                     x, W, xb, wtb);
  hipLaunchKernelGGL(k_hproj, dim3(B * IT), dim3(256), 0, stream, xb, wtb, a, h_t, el, er);
  hipLaunchKernelGGL(k_attn, dim3(B * IT * 2), dim3(1024), 0, stream, adj, h_t, el, er, pnum, pden);
  hipLaunchKernelGGL(k_final, dim3(B * IT), dim3(1024), 0, stream, pnum, pden, out);
}

// Round 2
// 135.858 us; speedup vs baseline: 1.1644x; 1.1644x over previous
//
#include <hip/hip_runtime.h>
#include <stdint.h>

#define LOG2E 1.4426950408889634f

typedef __bf16 v8bf __attribute__((ext_vector_type(8)));
typedef float v16f __attribute__((ext_vector_type(16)));

static constexpr int B = 4, N = 2048, FIN = 128, H = 4, DK = 32;
static constexpr int IT = N / 32;   // 64 i-tiles
static constexpr int PACK_BLOCKS = B * N * N / 1024;          // 16384 (256 thr = 4 waves x 256 ints)
static constexpr int PREP_BLOCKS = (B * N * FIN + H * DK * FIN) / 256;  // 4160

__device__ __forceinline__ float exp2_fast(float x) {
#if __has_builtin(__builtin_amdgcn_exp2f)
  return __builtin_amdgcn_exp2f(x);
#else
  float r;
  asm("v_exp_f32 %0, %1" : "=v"(r) : "v"(x));
  return r;
#endif
}

__device__ __forceinline__ unsigned int bf16_rne(float f) {
  unsigned int u = __builtin_bit_cast(unsigned int, f);
  u += 0x7FFFu + ((u >> 16) & 1u);
  return u >> 16;
}

// ------- kernel 0 (merged): adj bit-pack + x->bf16 cast + wtb[h][d][f] bf16 -------
// blocks [0, PACK_BLOCKS): pack adjacency -> adjb[b][i][j/32] (wave = 256 ints)
// blocks [PACK_BLOCKS, +PREP_BLOCKS): elementwise cast
__global__ __launch_bounds__(256) void k_prep(const int* __restrict__ adj,
                                              const float* __restrict__ x,
                                              const float* __restrict__ W,
                                              unsigned int* __restrict__ adjb,
                                              unsigned short* __restrict__ xb,
                                              unsigned short* __restrict__ wtb) {
  int bid = blockIdx.x;
  int tid = threadIdx.x;
  if (bid < PACK_BLOCKS) {
    int wid = (bid * 256 + tid) >> 6;      // global wave id, 256 consecutive ints each
    int lane = tid & 63;
    const int* p = adj + (size_t)wid * 256 + lane;
    unsigned long long m0 = __ballot(p[0] != 0);
    unsigned long long m1 = __ballot(p[64] != 0);
    unsigned long long m2 = __ballot(p[128] != 0);
    unsigned long long m3 = __ballot(p[192] != 0);
    if (lane == 0) {
      uint4 v0 = {(unsigned)m0, (unsigned)(m0 >> 32), (unsigned)m1, (unsigned)(m1 >> 32)};
      uint4 v1 = {(unsigned)m2, (unsigned)(m2 >> 32), (unsigned)m3, (unsigned)(m3 >> 32)};
      uint4* dst = (uint4*)(adjb + (size_t)wid * 8);
      dst[0] = v0;
      dst[1] = v1;
    }
    return;
  }
  int idx = (bid - PACK_BLOCKS) * 256 + tid;
  constexpr int TX = B * N * FIN;          // 1048576
  if (idx < TX) {
    xb[idx] = (unsigned short)bf16_rne(x[idx]);
  } else {
    int j = idx - TX;                      // < H*DK*FIN = 16384
    int h = j >> 12, r = j & 4095, d = r >> 7, f = r & 127;
    wtb[j] = (unsigned short)bf16_rne(W[(h * FIN + f) * DK + d]);
  }
}

// ---------------- kernel 1: h projection via MFMA; h_t[bh][d][n] + el/er ----------------
__global__ __launch_bounds__(256) void k_hproj(const unsigned short* __restrict__ xb,
                                               const unsigned short* __restrict__ wtb,
                                               const float* __restrict__ a,
                                               unsigned short* __restrict__ h_t,
                                               float* __restrict__ el,
                                               float* __restrict__ er) {
  int blk = blockIdx.x;
  int b = blk >> 6, it = blk & 63;
  int tid = threadIdx.x;
  int head = tid >> 6, lane = tid & 63;
  int lrow = lane & 31, kh = lane >> 5;
  int bh = b * H + head;
  int n = it * 32 + lrow;
  const unsigned short* xp = xb + (b * N + n) * FIN + kh * 8;
  const unsigned short* wp = wtb + (head * DK + lrow) * FIN + kh * 8;
  v16f acc = {};
#pragma unroll
  for (int s = 0; s < FIN / 16; ++s) {
    v8bf av = __builtin_bit_cast(v8bf, *(const int4*)(wp + s * 16));
    v8bf bv = __builtin_bit_cast(v8bf, *(const int4*)(xp + s * 16));
    acc = __builtin_amdgcn_mfma_f32_32x32x16_bf16(av, bv, acc, 0, 0, 0);
  }
  float pel = 0.f, per = 0.f;
#pragma unroll
  for (int r = 0; r < 16; ++r) {
    int d = (r & 3) + 8 * (r >> 2) + 4 * kh;   // C/D row mapping (32x32 bf16)
    float hv = acc[r];
    h_t[(bh * DK + d) * N + n] = (unsigned short)bf16_rne(hv);
    pel = fmaf(hv, a[head * 2 * DK + d], pel);
    per = fmaf(hv, a[head * 2 * DK + DK + d], per);
  }
  pel += __shfl_xor(pel, 32);
  per += __shfl_xor(per, 32);
  if (kh == 0) {
    el[bh * N + n] = pel * LOG2E;
    er[bh * N + n] = per * LOG2E;
  }
}

// ---------------- kernel 2: fused attention over a j-half, partials to ws ----------------
// grid = B*IT*2; block = 1024 threads = 16 waves = (jq 0..3) x (head 0..3)
// wave covers 256 j of its block's 1024-j half; adjb bits preloaded (2 x uint4, L2-resident)
// 2 blocks/CU (32 waves/CU) via __launch_bounds__(1024, 8); LDS 66KB*2 = 132KB < 160KB.
__global__ __launch_bounds__(1024, 8) void k_attn(const unsigned int* __restrict__ adjb,
                                                  const unsigned short* __restrict__ h_t,
                                                  const float* __restrict__ el,
                                                  const float* __restrict__ er,
                                                  float* __restrict__ pnum,
                                                  float* __restrict__ pden) {
  __shared__ float part4[4][H][1024];   // [jq][head][i*32+d] private slices, no atomics
  __shared__ float lsh4[4][H][32];      // [jq][head][i]
  int blk = blockIdx.x;                 // 0..511
  int bit = blk >> 1, jh = blk & 1;
  int b = bit >> 6, it = bit & 63;
  int tid = threadIdx.x;
  int wave = tid >> 6;
  int head = wave & 3, jq = wave >> 2;
  int lane = tid & 63, lrow = lane & 31, kh = lane >> 5;
  int ig = it * 32 + lrow, bh = b * H + head;

  float eli = el[bh * N + ig];
  int j0 = jh * 1024 + jq * 256 + kh * 8;
  const float* erp = er + bh * N + j0;
  const unsigned short* hp = h_t + (size_t)(bh * DK + lrow) * N + j0;

  // this lane's adjacency bits for its 256-j quarter (one-time latency, L2-resident)
  const uint4* abp = (const uint4*)(adjb + (size_t)(b * N + ig) * 64 + jh * 32 + jq * 8);
  uint4 ab0 = abp[0], ab1 = abp[1];
  unsigned adw[8] = {ab0.x, ab0.y, ab0.z, ab0.w, ab1.x, ab1.y, ab1.z, ab1.w};
  int shkh = kh * 8;

  v16f acc = {};
  float lsum = 0.f;
  float4 Ea = *(const float4*)erp;
  float4 Eb = *(const float4*)(erp + 4);
  int4 Hb = *(const int4*)hp;
#pragma unroll
  for (int s = 0; s < 16; ++s) {
    float4 ea = Ea, eb = Eb;
    int4 hb = Hb;
    if (s + 1 < 16) {
      int o = (s + 1) * 16;
      Ea = *(const float4*)(erp + o);
      Eb = *(const float4*)(erp + o + 4);
      Hb = *(const int4*)(hp + o);
    }
    unsigned mb = (adw[s >> 1] >> (((s & 1) * 16) + shkh)) & 0xFFu;
    float ev[8] = {ea.x, ea.y, ea.z, ea.w, eb.x, eb.y, eb.z, eb.w};
    unsigned ub[8];
#pragma unroll
    for (int k = 0; k < 8; ++k) {
      float tt = eli + ev[k];
      tt = fmaxf(tt, 0.2f * tt);            // leaky relu (log2e pre-folded)
      float pv = exp2_fast(tt);
      unsigned u = __builtin_bit_cast(unsigned, pv) & 0xFFFF0000u;
      u = (mb & (1u << k)) ? u : 0u;        // adjacency bit mask
      ub[k] = u;
      lsum += __builtin_bit_cast(float, u); // truncated value: num/den consistent
    }
    unsigned u0 = __builtin_amdgcn_perm(ub[1], ub[0], 0x07060302u);
    unsigned u1 = __builtin_amdgcn_perm(ub[3], ub[2], 0x07060302u);
    unsigned u2 = __builtin_amdgcn_perm(ub[5], ub[4], 0x07060302u);
    unsigned u3 = __builtin_amdgcn_perm(ub[7], ub[6], 0x07060302u);
    uint4 au = {u0, u1, u2, u3};
    v8bf av = __builtin_bit_cast(v8bf, au);
    v8bf hv = __builtin_bit_cast(v8bf, hb);
    acc = __builtin_amdgcn_mfma_f32_32x32x16_bf16(av, hv, acc, 0, 0, 0);
  }

  lsum += __shfl_xor(lsum, 32);
  if (lane < 32) lsh4[jq][head][lane] = lsum;
#pragma unroll
  for (int r = 0; r < 16; ++r) {
    int rowl = (r & 3) + 8 * (r >> 2) + 4 * kh;   // i-row within tile
    part4[jq][head][rowl * 32 + lrow] = acc[r];   // private slice: plain store
  }
  __syncthreads();

  // combine 4 jq slices; 4096 partial outputs / 1024 threads = one float4 each
  int e = tid * 4;
  int rh = e >> 10, rr = e & 1023;
  float4 q0 = *(const float4*)&part4[0][rh][rr];
  float4 q1 = *(const float4*)&part4[1][rh][rr];
  float4 q2 = *(const float4*)&part4[2][rh][rr];
  float4 q3 = *(const float4*)&part4[3][rh][rr];
  float4 s4;
  s4.x = (q0.x + q1.x) + (q2.x + q3.x);
  s4.y = (q0.y + q1.y) + (q2.y + q3.y);
  s4.z = (q0.z + q1.z) + (q2.z + q3.z);
  s4.w = (q0.w + q1.w) + (q2.w + q3.w);
  *(float4*)&pnum[(size_t)blk * 4096 + e] = s4;
  if (tid < 128) {
    float d = (lsh4[0][tid >> 5][tid & 31] + lsh4[1][tid >> 5][tid & 31]) +
              (lsh4[2][tid >> 5][tid & 31] + lsh4[3][tid >> 5][tid & 31]);
    pden[blk * 128 + tid] = d;
  }
}

// ---------------- kernel 3: combine j-halves + normalize ----------------
__global__ __launch_bounds__(1024) void k_final(const float* __restrict__ pnum,
                                                const float* __restrict__ pden,
                                                float* __restrict__ out) {
  int bit = blockIdx.x;            // 0..255 = (b, it)
  int b = bit >> 6, it = bit & 63;
  int tid = threadIdx.x;
  int e = tid * 4;
  int rh = e >> 10, ri = (e >> 5) & 31, rd = e & 31;
  size_t p0 = (size_t)(bit * 2) * 4096 + e;
  float4 n0 = *(const float4*)&pnum[p0];
  float4 n1 = *(const float4*)&pnum[p0 + 4096];
  float d = pden[bit * 2 * 128 + rh * 32 + ri] + pden[(bit * 2 + 1) * 128 + rh * 32 + ri];
  float inv = 1.0f / d;
  float4 o;
  o.x = (n0.x + n1.x) * inv;
  o.y = (n0.y + n1.y) * inv;
  o.z = (n0.z + n1.z) * inv;
  o.w = (n0.w + n1.w) * inv;
  *(float4*)&out[(size_t)((b * H + rh) * N + it * 32 + ri) * DK + rd] = o;
}

extern "C" void kernel_launch(void* const* d_in, const int* in_sizes, int n_in,
                              void* d_out, int out_size, void* d_ws, size_t ws_size,
                              hipStream_t stream) {
  const float* x = (const float*)d_in[0];
  const int* adj = (const int*)d_in[1];
  const float* W = (const float*)d_in[2];
  const float* a = (const float*)d_in[3];
  float* out = (float*)d_out;
  char* ws = (char*)d_ws;

  unsigned short* h_t = (unsigned short*)(ws);             // 2 MB   [B][H][DK][N]
  float* el = (float*)(ws + 0x200000);                     // 128 KB
  float* er = (float*)(ws + 0x220000);                     // 128 KB
  unsigned short* wtb = (unsigned short*)(ws + 0x240000);  // 32 KB
  unsigned int* adjb = (unsigned int*)(ws + 0x250000);     // 2 MB bitmask
  unsigned short* xb = (unsigned short*)(ws + 0x450000);   // 2 MB
  float* pnum = (float*)(ws + 0x650000);                   // 8 MB   [512][H][32][32]
  float* pden = (float*)(ws + 0xE50000);                   // 256 KB [512][H][32]
  // total ~14.8 MB

  hipLaunchKernelGGL(k_prep, dim3(PACK_BLOCKS + PREP_BLOCKS), dim3(256), 0, stream,
                     adj, x, W, adjb, xb, wtb);
  hipLaunchKernelGGL(k_hproj, dim3(B * IT), dim3(256), 0, stream, xb, wtb, a, h_t, el, er);
  hipLaunchKernelGGL(k_attn, dim3(B * IT * 2), dim3(1024), 0, stream, adjb, h_t, el, er, pnum, pden);
  hipLaunchKernelGGL(k_final, dim3(B * IT), dim3(1024), 0, stream, pnum, pden, out);
}

// Round 3
// 128.894 us; speedup vs baseline: 1.2273x; 1.0540x over previous
//
#include <hip/hip_runtime.h>
#include <stdint.h>

#define LOG2E 1.4426950408889634f

typedef __bf16 v8bf __attribute__((ext_vector_type(8)));
typedef float v16f __attribute__((ext_vector_type(16)));

static constexpr int B = 4, N = 2048, FIN = 128, H = 4, DK = 32;
static constexpr int IT = N / 32;   // 64 i-tiles
static constexpr int PACK_BLOCKS = B * N * N / 1024;          // 16384 (256 thr = 4 waves x 256 ints)
static constexpr int PREP_BLOCKS = (B * N * FIN + H * DK * FIN) / 256;  // 4160

__device__ __forceinline__ float exp2_fast(float x) {
#if __has_builtin(__builtin_amdgcn_exp2f)
  return __builtin_amdgcn_exp2f(x);
#else
  float r;
  asm("v_exp_f32 %0, %1" : "=v"(r) : "v"(x));
  return r;
#endif
}

__device__ __forceinline__ unsigned int bf16_rne(float f) {
  unsigned int u = __builtin_bit_cast(unsigned int, f);
  u += 0x7FFFu + ((u >> 16) & 1u);
  return u >> 16;
}

// ------- kernel 0 (merged): adj bit-pack + x->bf16 cast + wtb[h][d][f] bf16 -------
__global__ __launch_bounds__(256) void k_prep(const int* __restrict__ adj,
                                              const float* __restrict__ x,
                                              const float* __restrict__ W,
                                              unsigned int* __restrict__ adjb,
                                              unsigned short* __restrict__ xb,
                                              unsigned short* __restrict__ wtb) {
  int bid = blockIdx.x;
  int tid = threadIdx.x;
  if (bid < PACK_BLOCKS) {
    int wid = (bid * 256 + tid) >> 6;      // global wave id, 256 consecutive ints each
    int lane = tid & 63;
    const int* p = adj + (size_t)wid * 256 + lane;
    unsigned long long m0 = __ballot(p[0] != 0);
    unsigned long long m1 = __ballot(p[64] != 0);
    unsigned long long m2 = __ballot(p[128] != 0);
    unsigned long long m3 = __ballot(p[192] != 0);
    if (lane == 0) {
      uint4 v0 = {(unsigned)m0, (unsigned)(m0 >> 32), (unsigned)m1, (unsigned)(m1 >> 32)};
      uint4 v1 = {(unsigned)m2, (unsigned)(m2 >> 32), (unsigned)m3, (unsigned)(m3 >> 32)};
      uint4* dst = (uint4*)(adjb + (size_t)wid * 8);
      dst[0] = v0;
      dst[1] = v1;
    }
    return;
  }
  int idx = (bid - PACK_BLOCKS) * 256 + tid;
  constexpr int TX = B * N * FIN;          // 1048576
  if (idx < TX) {
    xb[idx] = (unsigned short)bf16_rne(x[idx]);
  } else {
    int j = idx - TX;                      // < H*DK*FIN = 16384
    int h = j >> 12, r = j & 4095, d = r >> 7, f = r & 127;
    wtb[j] = (unsigned short)bf16_rne(W[(h * FIN + f) * DK + d]);
  }
}

// ---------------- kernel 1: h projection via MFMA; h_t[bh][d][n] + el/er ----------------
__global__ __launch_bounds__(256) void k_hproj(const unsigned short* __restrict__ xb,
                                               const unsigned short* __restrict__ wtb,
                                               const float* __restrict__ a,
                                               unsigned short* __restrict__ h_t,
                                               float* __restrict__ el,
                                               float* __restrict__ er) {
  int blk = blockIdx.x;
  int b = blk >> 6, it = blk & 63;
  int tid = threadIdx.x;
  int head = tid >> 6, lane = tid & 63;
  int lrow = lane & 31, kh = lane >> 5;
  int bh = b * H + head;
  int n = it * 32 + lrow;
  const unsigned short* xp = xb + (b * N + n) * FIN + kh * 8;
  const unsigned short* wp = wtb + (head * DK + lrow) * FIN + kh * 8;
  v16f acc = {};
#pragma unroll
  for (int s = 0; s < FIN / 16; ++s) {
    v8bf av = __builtin_bit_cast(v8bf, *(const int4*)(wp + s * 16));
    v8bf bv = __builtin_bit_cast(v8bf, *(const int4*)(xp + s * 16));
    acc = __builtin_amdgcn_mfma_f32_32x32x16_bf16(av, bv, acc, 0, 0, 0);
  }
  float pel = 0.f, per = 0.f;
#pragma unroll
  for (int r = 0; r < 16; ++r) {
    int d = (r & 3) + 8 * (r >> 2) + 4 * kh;   // C/D row mapping (32x32 bf16)
    float hv = acc[r];
    h_t[(bh * DK + d) * N + n] = (unsigned short)bf16_rne(hv);
    pel = fmaf(hv, a[head * 2 * DK + d], pel);
    per = fmaf(hv, a[head * 2 * DK + DK + d], per);
  }
  pel += __shfl_xor(pel, 32);
  per += __shfl_xor(per, 32);
  if (kh == 0) {
    el[bh * N + n] = pel * LOG2E;
    er[bh * N + n] = per * LOG2E;
  }
}

// ---------------- kernel 2: fused attention over a j-half, partials to ws ----------------
// grid = B*IT*2; block = 1024 threads = 16 waves = (jq 0..3) x (head 0..3)
// er staged in LDS (aliased into part4, barrier-separated); h_t prefetched 2 deep.
// 2 blocks/CU (32 waves/CU) via __launch_bounds__(1024, 8); LDS 66KB*2 = 132KB < 160KB.
__global__ __launch_bounds__(1024, 8) void k_attn(const unsigned int* __restrict__ adjb,
                                                  const unsigned short* __restrict__ h_t,
                                                  const float* __restrict__ el,
                                                  const float* __restrict__ er,
                                                  float* __restrict__ pnum,
                                                  float* __restrict__ pden) {
  __shared__ __align__(16) float part4[4][H][1024];  // 64KB; part4[0] aliased as er stage in loop
  __shared__ float lsh4[4][H][32];      // [jq][head][i]
  int blk = blockIdx.x;                 // 0..511
  int bit = blk >> 1, jh = blk & 1;
  int b = bit >> 6, it = bit & 63;
  int tid = threadIdx.x;
  int wave = tid >> 6;
  int head = wave & 3, jq = wave >> 2;
  int lane = tid & 63, lrow = lane & 31, kh = lane >> 5;
  int ig = it * 32 + lrow, bh = b * H + head;

  // stage this j-half's er for all 4 heads into LDS: 4096 floats, 4/thread, coalesced
  {
    int hh = tid >> 8, jl = (tid & 255) * 4;
    *(float4*)&part4[0][hh][jl] = *(const float4*)&er[(b * H + hh) * N + jh * 1024 + jl];
  }

  float eli = el[bh * N + ig];
  int j0 = jh * 1024 + jq * 256 + kh * 8;
  const unsigned short* hp = h_t + (size_t)(bh * DK + lrow) * N + j0;
  int jql = jq * 256 + kh * 8;          // j-local base into ers LDS

  // this lane's adjacency bits for its 256-j quarter (one-time latency, L2-resident)
  const uint4* abp = (const uint4*)(adjb + (size_t)(b * N + ig) * 64 + jh * 32 + jq * 8);
  uint4 ab0 = abp[0], ab1 = abp[1];
  unsigned adw[8] = {ab0.x, ab0.y, ab0.z, ab0.w, ab1.x, ab1.y, ab1.z, ab1.w};
  int shkh = kh * 8;

  // h_t prefetch, 2 deep (issued before barrier: global, no LDS dependency)
  int4 hreg0 = *(const int4*)hp;
  int4 hreg1 = *(const int4*)(hp + 16);

  __syncthreads();   // er stage visible

  v16f acc = {};
  float lsum = 0.f;
  float4 Ea = *(const float4*)&part4[0][head][jql];        // LDS, s=0
  float4 Eb = *(const float4*)&part4[0][head][jql + 4];
#pragma unroll
  for (int s = 0; s < 16; ++s) {
    int4 hb = (s & 1) ? hreg1 : hreg0;
    if (s + 2 < 16) {
      int4 nv = *(const int4*)(hp + (s + 2) * 16);
      if (s & 1) hreg1 = nv; else hreg0 = nv;
    }
    float4 ea = Ea, eb = Eb;
    if (s + 1 < 16) {
      Ea = *(const float4*)&part4[0][head][jql + (s + 1) * 16];
      Eb = *(const float4*)&part4[0][head][jql + (s + 1) * 16 + 4];
    }
    unsigned mb = (adw[s >> 1] >> (((s & 1) * 16) + shkh)) & 0xFFu;
    float ev[8] = {ea.x, ea.y, ea.z, ea.w, eb.x, eb.y, eb.z, eb.w};
    unsigned ub[8];
#pragma unroll
    for (int k = 0; k < 8; ++k) {
      float tt = eli + ev[k];
      tt = fmaxf(tt, 0.2f * tt);            // leaky relu (log2e pre-folded)
      float pv = exp2_fast(tt);
      unsigned u = __builtin_bit_cast(unsigned, pv) & 0xFFFF0000u;
      u = (mb & (1u << k)) ? u : 0u;        // adjacency bit mask
      ub[k] = u;
      lsum += __builtin_bit_cast(float, u); // truncated value: num/den consistent
    }
    unsigned u0 = __builtin_amdgcn_perm(ub[1], ub[0], 0x07060302u);
    unsigned u1 = __builtin_amdgcn_perm(ub[3], ub[2], 0x07060302u);
    unsigned u2 = __builtin_amdgcn_perm(ub[5], ub[4], 0x07060302u);
    unsigned u3 = __builtin_amdgcn_perm(ub[7], ub[6], 0x07060302u);
    uint4 au = {u0, u1, u2, u3};
    v8bf av = __builtin_bit_cast(v8bf, au);
    v8bf hv = __builtin_bit_cast(v8bf, hb);
    acc = __builtin_amdgcn_mfma_f32_32x32x16_bf16(av, hv, acc, 0, 0, 0);
  }

  lsum += __shfl_xor(lsum, 32);
  if (lane < 32) lsh4[jq][head][lane] = lsum;   // lsh4 separate: safe before barrier

  __syncthreads();   // all er LDS reads done before part4 overwrite

#pragma unroll
  for (int r = 0; r < 16; ++r) {
    int rowl = (r & 3) + 8 * (r >> 2) + 4 * kh;   // i-row within tile
    part4[jq][head][rowl * 32 + lrow] = acc[r];   // private slice: plain store
  }
  __syncthreads();

  // combine 4 jq slices; 4096 partial outputs / 1024 threads = one float4 each
  int e = tid * 4;
  int rh = e >> 10, rr = e & 1023;
  float4 q0 = *(const float4*)&part4[0][rh][rr];
  float4 q1 = *(const float4*)&part4[1][rh][rr];
  float4 q2 = *(const float4*)&part4[2][rh][rr];
  float4 q3 = *(const float4*)&part4[3][rh][rr];
  float4 s4;
  s4.x = (q0.x + q1.x) + (q2.x + q3.x);
  s4.y = (q0.y + q1.y) + (q2.y + q3.y);
  s4.z = (q0.z + q1.z) + (q2.z + q3.z);
  s4.w = (q0.w + q1.w) + (q2.w + q3.w);
  *(float4*)&pnum[(size_t)blk * 4096 + e] = s4;
  if (tid < 128) {
    float d = (lsh4[0][tid >> 5][tid & 31] + lsh4[1][tid >> 5][tid & 31]) +
              (lsh4[2][tid >> 5][tid & 31] + lsh4[3][tid >> 5][tid & 31]);
    pden[blk * 128 + tid] = d;
  }
}

// ---------------- kernel 3: combine j-halves + normalize ----------------
__global__ __launch_bounds__(1024) void k_final(const float* __restrict__ pnum,
                                                const float* __restrict__ pden,
                                                float* __restrict__ out) {
  int bit = blockIdx.x;            // 0..255 = (b, it)
  int b = bit >> 6, it = bit & 63;
  int tid = threadIdx.x;
  int e = tid * 4;
  int rh = e >> 10, ri = (e >> 5) & 31, rd = e & 31;
  size_t p0 = (size_t)(bit * 2) * 4096 + e;
  float4 n0 = *(const float4*)&pnum[p0];
  float4 n1 = *(const float4*)&pnum[p0 + 4096];
  float d = pden[bit * 2 * 128 + rh * 32 + ri] + pden[(bit * 2 + 1) * 128 + rh * 32 + ri];
  float inv = 1.0f / d;
  float4 o;
  o.x = (n0.x + n1.x) * inv;
  o.y = (n0.y + n1.y) * inv;
  o.z = (n0.z + n1.z) * inv;
  o.w = (n0.w + n1.w) * inv;
  *(float4*)&out[(size_t)((b * H + rh) * N + it * 32 + ri) * DK + rd] = o;
}

extern "C" void kernel_launch(void* const* d_in, const int* in_sizes, int n_in,
                              void* d_out, int out_size, void* d_ws, size_t ws_size,
                              hipStream_t stream) {
  const float* x = (const float*)d_in[0];
  const int* adj = (const int*)d_in[1];
  const float* W = (const float*)d_in[2];
  const float* a = (const float*)d_in[3];
  float* out = (float*)d_out;
  char* ws = (char*)d_ws;

  unsigned short* h_t = (unsigned short*)(ws);             // 2 MB   [B][H][DK][N]
  float* el = (float*)(ws + 0x200000);                     // 128 KB
  float* er = (float*)(ws + 0x220000);                     // 128 KB
  unsigned short* wtb = (unsigned short*)(ws + 0x240000);  // 32 KB
  unsigned int* adjb = (unsigned int*)(ws + 0x250000);     // 2 MB bitmask
  unsigned short* xb = (unsigned short*)(ws + 0x450000);   // 2 MB
  float* pnum = (float*)(ws + 0x650000);                   // 8 MB   [512][H][32][32]
  float* pden = (float*)(ws + 0xE50000);                   // 256 KB [512][H][32]
  // total ~14.8 MB

  hipLaunchKernelGGL(k_prep, dim3(PACK_BLOCKS + PREP_BLOCKS), dim3(256), 0, stream,
                     adj, x, W, adjb, xb, wtb);
  hipLaunchKernelGGL(k_hproj, dim3(B * IT), dim3(256), 0, stream, xb, wtb, a, h_t, el, er);
  hipLaunchKernelGGL(k_attn, dim3(B * IT * 2), dim3(1024), 0, stream, adjb, h_t, el, er, pnum, pden);
  hipLaunchKernelGGL(k_final, dim3(B * IT), dim3(1024), 0, stream, pnum, pden, out);
}